// Round 3
// baseline (48.829 us; speedup 1.0000x reference)
//
#include <hip/hip_runtime.h>
#include <math.h>

#define T_SAMPLES 100
#define K1_BLOCKS 512
#define THREADS 256
#define NWAVES (THREADS / 64)
#define NSUB 8          // one sub-histogram per 32-lane half-wave
#define HPAD 104        // padded bin stride (104 mod 32 = 8) to spread LDS banks
#define HIST_BASE 1040  // float index where per-block hist regions start
#define HIST_STRIDE 200 // floats per block region: 100 counts + 100 sums
#define MAX_HB 256      // max histogram blocks

// ws float layout:
//   u[0]                      : last-block counter for K2 (zeroed by K1 each call)
//   f[16 .. 16+K1_BLOCKS)     : per-block min partials (of losses)
//   f[16+K1B .. 16+2*K1B)     : per-block max partials
//   f[HIST_BASE + b*200 + j]  : block b's count for bin j   (j < 100)
//   f[HIST_BASE + b*200+100+j]: block b's sum for bin j
// Max footprint: (1040 + 256*200)*4 ≈ 209 KB; adaptively shrunk to ws_size.

__global__ void __launch_bounds__(THREADS) cvar_pass1(const float* __restrict__ pnl,
                                                      int n, float* __restrict__ ws) {
    if (blockIdx.x == 0 && threadIdx.x == 0) ((unsigned*)ws)[0] = 0u;

    int tid = blockIdx.x * THREADS + threadIdx.x;
    int stride = gridDim.x * THREADS;
    float lmin = INFINITY, lmax = -INFINITY;
    int n4 = n >> 2;
    const float4* p4 = (const float4*)pnl;
    for (int i = tid; i < n4; i += stride) {
        float4 v = p4[i];
        lmin = fminf(lmin, fminf(fminf(-v.x, -v.y), fminf(-v.z, -v.w)));
        lmax = fmaxf(lmax, fmaxf(fmaxf(-v.x, -v.y), fmaxf(-v.z, -v.w)));
    }
    for (int i = (n4 << 2) + tid; i < n; i += stride) {
        float l = -pnl[i];
        lmin = fminf(lmin, l);
        lmax = fmaxf(lmax, l);
    }
    #pragma unroll
    for (int off = 32; off > 0; off >>= 1) {
        lmin = fminf(lmin, __shfl_down(lmin, off, 64));
        lmax = fmaxf(lmax, __shfl_down(lmax, off, 64));
    }
    __shared__ float smin[NWAVES], smax[NWAVES];
    int lane = threadIdx.x & 63, wid = threadIdx.x >> 6;
    if (lane == 0) { smin[wid] = lmin; smax[wid] = lmax; }
    __syncthreads();
    if (threadIdx.x == 0) {
        float a = smin[0], b = smax[0];
        for (int w = 1; w < NWAVES; ++w) { a = fminf(a, smin[w]); b = fmaxf(b, smax[w]); }
        ws[16 + blockIdx.x] = a;
        ws[16 + K1_BLOCKS + blockIdx.x] = b;
    }
}

__global__ void __launch_bounds__(THREADS) cvar_pass2(const float* __restrict__ pnl,
                                                      int n, float* __restrict__ ws,
                                                      float* __restrict__ out, int nb) {
    __shared__ unsigned scnt[NSUB][HPAD];
    __shared__ float ssum[NSUB][HPAD];
    __shared__ float smin[NWAVES], smax[NWAVES];
    __shared__ float s_tmin, s_tmax;
    __shared__ bool amLast;
    __shared__ float fc[T_SAMPLES], fs[T_SAMPLES];
    __shared__ float sred[NWAVES];

    for (int i = threadIdx.x; i < NSUB * HPAD; i += THREADS) {
        (&scnt[0][0])[i] = 0u;
        (&ssum[0][0])[i] = 0.0f;
    }

    // every block redundantly reduces K1's partials (L2-resident, 4 KB)
    float lmin = INFINITY, lmax = -INFINITY;
    for (int i = threadIdx.x; i < K1_BLOCKS; i += THREADS) {
        lmin = fminf(lmin, ws[16 + i]);
        lmax = fmaxf(lmax, ws[16 + K1_BLOCKS + i]);
    }
    #pragma unroll
    for (int off = 32; off > 0; off >>= 1) {
        lmin = fminf(lmin, __shfl_down(lmin, off, 64));
        lmax = fmaxf(lmax, __shfl_down(lmax, off, 64));
    }
    int lane = threadIdx.x & 63, wid = threadIdx.x >> 6;
    if (lane == 0) { smin[wid] = lmin; smax[wid] = lmax; }
    __syncthreads();
    if (threadIdx.x == 0) {
        float a = smin[0], b = smax[0];
        for (int w = 1; w < NWAVES; ++w) { a = fminf(a, smin[w]); b = fmaxf(b, smax[w]); }
        s_tmin = a;
        s_tmax = b;
    }
    __syncthreads();

    const float t_min = s_tmin, t_max = s_tmax;
    const float range = t_max - t_min;
    const float inv_dt = (range > 0.0f) ? (float)(T_SAMPLES - 1) / range : 0.0f;

    // half-wave-privatized LDS histogram (32-lane contention domain)
    const int sub = (threadIdx.x >> 5) & (NSUB - 1);
    int tid = blockIdx.x * THREADS + threadIdx.x;
    int stride = gridDim.x * THREADS;
    int n4 = n >> 2;
    const float4* p4 = (const float4*)pnl;
    for (int i = tid; i < n4; i += stride) {
        float4 v = p4[i];
        float l[4] = {-v.x, -v.y, -v.z, -v.w};
        #pragma unroll
        for (int k = 0; k < 4; ++k) {
            int b = (int)((l[k] - t_min) * inv_dt);
            b = b < 0 ? 0 : (b > T_SAMPLES - 1 ? T_SAMPLES - 1 : b);
            atomicAdd(&scnt[sub][b], 1u);
            atomicAdd(&ssum[sub][b], l[k]);
        }
    }
    for (int i = (n4 << 2) + tid; i < n; i += stride) {
        float l = -pnl[i];
        int b = (int)((l - t_min) * inv_dt);
        b = b < 0 ? 0 : (b > T_SAMPLES - 1 ? T_SAMPLES - 1 : b);
        atomicAdd(&scnt[sub][b], 1u);
        atomicAdd(&ssum[sub][b], l);
    }
    __syncthreads();

    // merge sub-hists -> this block's private global region (NO atomics)
    float* reg = ws + HIST_BASE + blockIdx.x * HIST_STRIDE;
    if (threadIdx.x < T_SAMPLES) {
        unsigned c = 0u;
        float s = 0.0f;
        #pragma unroll
        for (int w = 0; w < NSUB; ++w) { c += scnt[w][threadIdx.x]; s += ssum[w][threadIdx.x]; }
        __hip_atomic_store(&reg[threadIdx.x], (float)c,
                           __ATOMIC_RELAXED, __HIP_MEMORY_SCOPE_AGENT);
        __hip_atomic_store(&reg[T_SAMPLES + threadIdx.x], s,
                           __ATOMIC_RELAXED, __HIP_MEMORY_SCOPE_AGENT);
    }
    __syncthreads();

    // last-arriving block computes the finale
    if (threadIdx.x == 0) {
        __threadfence();
        unsigned prev = atomicAdd((unsigned*)ws, 1u);
        amLast = (prev == (unsigned)(nb - 1));
    }
    __syncthreads();
    if (!amLast) return;
    __threadfence();

    if (threadIdx.x < T_SAMPLES) {
        float C = 0.0f, L = 0.0f;
        const float* base = ws + HIST_BASE + threadIdx.x;
        #pragma unroll 4
        for (int b = 0; b < nb; ++b) {
            C += __hip_atomic_load(base + b * HIST_STRIDE,
                                   __ATOMIC_RELAXED, __HIP_MEMORY_SCOPE_AGENT);
            L += __hip_atomic_load(base + b * HIST_STRIDE + T_SAMPLES,
                                   __ATOMIC_RELAXED, __HIP_MEMORY_SCOPE_AGENT);
        }
        fc[threadIdx.x] = C;
        fs[threadIdx.x] = L;
    }
    __syncthreads();

    const float dt = range / (float)(T_SAMPLES - 1);
    float cvar = INFINITY;
    int j = threadIdx.x;
    if (j < T_SAMPLES) {
        float C = 0.0f, L = 0.0f;
        for (int k = j; k < T_SAMPLES; ++k) { C += fc[k]; L += fs[k]; }
        float tj = (j == T_SAMPLES - 1) ? t_max : t_min + (float)j * dt;
        float S = L - tj * C;                   // == sum relu(l - tj)
        cvar = tj + S * (20.0f / (float)n);     // mean / (1 - 0.95)
    }
    #pragma unroll
    for (int off = 32; off > 0; off >>= 1)
        cvar = fminf(cvar, __shfl_down(cvar, off, 64));
    if (lane == 0) sred[wid] = cvar;
    __syncthreads();
    if (threadIdx.x == 0) {
        float m = sred[0];
        for (int w = 1; w < NWAVES; ++w) m = fminf(m, sred[w]);
        out[0] = m;
    }
}

extern "C" void kernel_launch(void* const* d_in, const int* in_sizes, int n_in,
                              void* d_out, int out_size, void* d_ws, size_t ws_size,
                              hipStream_t stream) {
    const float* pnl = (const float*)d_in[0];
    int n = in_sizes[0];
    float* ws = (float*)d_ws;
    float* out = (float*)d_out;

    // adaptive hist-block count so the per-block regions fit ws_size
    long avail = (long)(ws_size / 4) - HIST_BASE;
    int nb = (int)(avail / HIST_STRIDE);
    nb = nb < 8 ? 8 : (nb > MAX_HB ? MAX_HB : nb);

    cvar_pass1<<<K1_BLOCKS, THREADS, 0, stream>>>(pnl, n, ws);
    cvar_pass2<<<nb, THREADS, 0, stream>>>(pnl, n, ws, out, nb);
}

// Round 4
// 36.431 us; speedup vs baseline: 1.3403x; 1.3403x over previous
//
#include <hip/hip_runtime.h>
#include <math.h>

#define T_SAMPLES 100
#define K1_BLOCKS 512
#define K2_BLOCKS 256
#define THREADS 256
#define NWAVES (THREADS / 64)
#define NSUB 8          // one sub-histogram per 32-lane half-wave
#define HPAD 104        // padded bin stride (104 mod 32 = 8) to spread LDS banks
#define PART_BASE 4096  // float index where transposed partial hists start

// ws float layout:
//   f[16 .. 16+K1_BLOCKS)        : per-block min partials (of losses)
//   f[16+K1B .. 16+2*K1B)        : per-block max partials
//   f[PART_BASE + j*nb + b]      : count partial, bin j, block b   (j < 100, b < nb)
//   f[PART_BASE + 100*nb + j*nb + b] : sum partial
// Footprint: (4096 + 200*nb)*4 bytes; nb adapted to ws_size (nb=256 -> 221 KB).

__global__ void __launch_bounds__(THREADS) cvar_pass1(const float* __restrict__ pnl,
                                                      int n, float* __restrict__ ws) {
    int tid = blockIdx.x * THREADS + threadIdx.x;
    int stride = gridDim.x * THREADS;
    float lmin = INFINITY, lmax = -INFINITY;
    int n4 = n >> 2;
    const float4* p4 = (const float4*)pnl;
    for (int i = tid; i < n4; i += stride) {
        float4 v = p4[i];
        lmin = fminf(lmin, fminf(fminf(-v.x, -v.y), fminf(-v.z, -v.w)));
        lmax = fmaxf(lmax, fmaxf(fmaxf(-v.x, -v.y), fmaxf(-v.z, -v.w)));
    }
    for (int i = (n4 << 2) + tid; i < n; i += stride) {
        float l = -pnl[i];
        lmin = fminf(lmin, l);
        lmax = fmaxf(lmax, l);
    }
    #pragma unroll
    for (int off = 32; off > 0; off >>= 1) {
        lmin = fminf(lmin, __shfl_down(lmin, off, 64));
        lmax = fmaxf(lmax, __shfl_down(lmax, off, 64));
    }
    __shared__ float smin[NWAVES], smax[NWAVES];
    int lane = threadIdx.x & 63, wid = threadIdx.x >> 6;
    if (lane == 0) { smin[wid] = lmin; smax[wid] = lmax; }
    __syncthreads();
    if (threadIdx.x == 0) {
        float a = smin[0], b = smax[0];
        for (int w = 1; w < NWAVES; ++w) { a = fminf(a, smin[w]); b = fmaxf(b, smax[w]); }
        ws[16 + blockIdx.x] = a;
        ws[16 + K1_BLOCKS + blockIdx.x] = b;
    }
}

__device__ __forceinline__ void reduce_minmax_partials(const float* __restrict__ ws,
                                                       float* s_tmin, float* s_tmax,
                                                       float* smin, float* smax) {
    float lmin = INFINITY, lmax = -INFINITY;
    for (int i = threadIdx.x; i < K1_BLOCKS; i += blockDim.x) {
        lmin = fminf(lmin, ws[16 + i]);
        lmax = fmaxf(lmax, ws[16 + K1_BLOCKS + i]);
    }
    #pragma unroll
    for (int off = 32; off > 0; off >>= 1) {
        lmin = fminf(lmin, __shfl_down(lmin, off, 64));
        lmax = fmaxf(lmax, __shfl_down(lmax, off, 64));
    }
    int lane = threadIdx.x & 63, wid = threadIdx.x >> 6;
    if (lane == 0) { smin[wid] = lmin; smax[wid] = lmax; }
    __syncthreads();
    if (threadIdx.x == 0) {
        float a = smin[0], b = smax[0];
        int nw = blockDim.x >> 6;
        for (int w = 1; w < nw; ++w) { a = fminf(a, smin[w]); b = fmaxf(b, smax[w]); }
        *s_tmin = a;
        *s_tmax = b;
    }
    __syncthreads();
}

__global__ void __launch_bounds__(THREADS) cvar_pass2(const float* __restrict__ pnl,
                                                      int n, float* __restrict__ ws,
                                                      int nb) {
    __shared__ unsigned scnt[NSUB][HPAD];
    __shared__ float ssum[NSUB][HPAD];
    __shared__ float smin[NWAVES], smax[NWAVES];
    __shared__ float s_tmin, s_tmax;

    for (int i = threadIdx.x; i < NSUB * HPAD; i += THREADS) {
        (&scnt[0][0])[i] = 0u;
        (&ssum[0][0])[i] = 0.0f;
    }
    reduce_minmax_partials(ws, &s_tmin, &s_tmax, smin, smax);

    const float t_min = s_tmin, t_max = s_tmax;
    const float range = t_max - t_min;
    const float inv_dt = (range > 0.0f) ? (float)(T_SAMPLES - 1) / range : 0.0f;

    const int sub = (threadIdx.x >> 5) & (NSUB - 1);
    int tid = blockIdx.x * THREADS + threadIdx.x;
    int stride = gridDim.x * THREADS;
    int n4 = n >> 2;
    const float4* p4 = (const float4*)pnl;
    for (int i = tid; i < n4; i += stride) {
        float4 v = p4[i];
        float l[4] = {-v.x, -v.y, -v.z, -v.w};
        #pragma unroll
        for (int k = 0; k < 4; ++k) {
            int b = (int)((l[k] - t_min) * inv_dt);
            b = b < 0 ? 0 : (b > T_SAMPLES - 1 ? T_SAMPLES - 1 : b);
            atomicAdd(&scnt[sub][b], 1u);
            atomicAdd(&ssum[sub][b], l[k]);
        }
    }
    for (int i = (n4 << 2) + tid; i < n; i += stride) {
        float l = -pnl[i];
        int b = (int)((l - t_min) * inv_dt);
        b = b < 0 ? 0 : (b > T_SAMPLES - 1 ? T_SAMPLES - 1 : b);
        atomicAdd(&scnt[sub][b], 1u);
        atomicAdd(&ssum[sub][b], l);
    }
    __syncthreads();

    // merge sub-hists -> transposed private slot (plain stores; kernel boundary
    // provides coherence for pass3)
    if (threadIdx.x < T_SAMPLES) {
        unsigned c = 0u;
        float s = 0.0f;
        #pragma unroll
        for (int w = 0; w < NSUB; ++w) { c += scnt[w][threadIdx.x]; s += ssum[w][threadIdx.x]; }
        ws[PART_BASE + threadIdx.x * nb + blockIdx.x] = (float)c;
        ws[PART_BASE + (T_SAMPLES + threadIdx.x) * nb + blockIdx.x] = s;
    }
}

__global__ void __launch_bounds__(512) cvar_pass3(float* __restrict__ ws,
                                                  float* __restrict__ out,
                                                  int n, int nb) {
    __shared__ float smin[8], smax[8];
    __shared__ float s_tmin, s_tmax;
    __shared__ float cq[T_SAMPLES][4], sq[T_SAMPLES][4];
    __shared__ float fc[T_SAMPLES], fs[T_SAMPLES];
    __shared__ float sred[8];

    reduce_minmax_partials(ws, &s_tmin, &s_tmax, smin, smax);
    const float t_min = s_tmin, t_max = s_tmax;
    const float range = t_max - t_min;

    // cross-block reduce of transposed partials: 4 lanes per bin, coalesced quads
    int t = threadIdx.x;
    int j = t >> 2, q = t & 3;
    if (t < 4 * T_SAMPLES) {
        const float* pc = ws + PART_BASE + j * nb;
        const float* ps = ws + PART_BASE + (T_SAMPLES + j) * nb;
        float C = 0.0f, L = 0.0f;
        #pragma unroll 8
        for (int b = q; b < nb; b += 4) {
            C += pc[b];
            L += ps[b];
        }
        cq[j][q] = C;
        sq[j][q] = L;
    }
    __syncthreads();
    if (t < T_SAMPLES) {
        fc[t] = (cq[t][0] + cq[t][1]) + (cq[t][2] + cq[t][3]);
        fs[t] = (sq[t][0] + sq[t][1]) + (sq[t][2] + sq[t][3]);
    }
    __syncthreads();

    const float dt = range / (float)(T_SAMPLES - 1);
    float cvar = INFINITY;
    if (t < T_SAMPLES) {
        float C = 0.0f, L = 0.0f;
        for (int k = t; k < T_SAMPLES; ++k) { C += fc[k]; L += fs[k]; }
        float tj = (t == T_SAMPLES - 1) ? t_max : t_min + (float)t * dt;
        float S = L - tj * C;                   // == sum relu(l - tj)
        cvar = tj + S * (20.0f / (float)n);     // mean / (1 - alpha)
    }
    #pragma unroll
    for (int off = 32; off > 0; off >>= 1)
        cvar = fminf(cvar, __shfl_down(cvar, off, 64));
    int lane = t & 63, wid = t >> 6;
    if (lane == 0) sred[wid] = cvar;
    __syncthreads();
    if (t == 0) {
        float m = sred[0];
        for (int w = 1; w < 8; ++w) m = fminf(m, sred[w]);
        out[0] = m;
    }
}

extern "C" void kernel_launch(void* const* d_in, const int* in_sizes, int n_in,
                              void* d_out, int out_size, void* d_ws, size_t ws_size,
                              hipStream_t stream) {
    const float* pnl = (const float*)d_in[0];
    int n = in_sizes[0];
    float* ws = (float*)d_ws;
    float* out = (float*)d_out;

    // adaptive histogram-block count so the partial regions fit ws_size
    long avail = (long)(ws_size / 4) - PART_BASE;
    int nb = (int)(avail / (2 * T_SAMPLES));
    nb = nb < 8 ? 8 : (nb > K2_BLOCKS ? K2_BLOCKS : nb);

    cvar_pass1<<<K1_BLOCKS, THREADS, 0, stream>>>(pnl, n, ws);
    cvar_pass2<<<nb, THREADS, 0, stream>>>(pnl, n, ws, nb);
    cvar_pass3<<<1, 512, 0, stream>>>(ws, out, n, nb);
}

// Round 5
// 25.670 us; speedup vs baseline: 1.9022x; 1.4192x over previous
//
#include <hip/hip_runtime.h>
#include <math.h>

#define T_SAMPLES 100
#define K1_BLOCKS 1024
#define HB_MAX 1024     // histogram blocks (4 per CU)
#define THREADS 256
#define NWAVES (THREADS / 64)
#define NSUB 8          // one sub-histogram per 32-lane half-wave
#define HPAD 104        // u64 elements per sub-hist row
#define PART64 2048     // u64 index where transposed packed partials start
#define FINAL_C 104448  // double index: per-bin total counts
#define FINAL_O 104548  // double index: per-bin total fixed-point offset sums

// ws layout:
//   f[16 .. 16+1024)          : per-block min partials (of losses)
//   f[16+1024 .. 16+2048)     : per-block max partials
//   u64[PART64 + j*nb + b]    : packed partial, bin j, hist-block b
//                               bits[45:63]=count, bits[0:44]=sum of frac*2^31
//   dbl[FINAL_C + j]          : total count for bin j
//   dbl[FINAL_O + j]          : total offset-sum (raw fixed point) for bin j
// Footprint ~850 KB at nb=1024; nb adapted down if ws_size is small.

__global__ void __launch_bounds__(THREADS) cvar_pass1(const float* __restrict__ pnl,
                                                      int n, float* __restrict__ ws) {
    int tid = blockIdx.x * THREADS + threadIdx.x;
    int stride = gridDim.x * THREADS;
    float lmin = INFINITY, lmax = -INFINITY;
    int n4 = n >> 2;
    const float4* p4 = (const float4*)pnl;
    for (int i = tid; i < n4; i += stride) {
        float4 v = p4[i];
        lmin = fminf(lmin, fminf(fminf(-v.x, -v.y), fminf(-v.z, -v.w)));
        lmax = fmaxf(lmax, fmaxf(fmaxf(-v.x, -v.y), fmaxf(-v.z, -v.w)));
    }
    for (int i = (n4 << 2) + tid; i < n; i += stride) {
        float l = -pnl[i];
        lmin = fminf(lmin, l);
        lmax = fmaxf(lmax, l);
    }
    #pragma unroll
    for (int off = 32; off > 0; off >>= 1) {
        lmin = fminf(lmin, __shfl_down(lmin, off, 64));
        lmax = fmaxf(lmax, __shfl_down(lmax, off, 64));
    }
    __shared__ float smin[NWAVES], smax[NWAVES];
    int lane = threadIdx.x & 63, wid = threadIdx.x >> 6;
    if (lane == 0) { smin[wid] = lmin; smax[wid] = lmax; }
    __syncthreads();
    if (threadIdx.x == 0) {
        float a = smin[0], b = smax[0];
        for (int w = 1; w < NWAVES; ++w) { a = fminf(a, smin[w]); b = fmaxf(b, smax[w]); }
        ws[16 + blockIdx.x] = a;
        ws[16 + K1_BLOCKS + blockIdx.x] = b;
    }
}

__device__ __forceinline__ void reduce_minmax_partials(const float* __restrict__ ws,
                                                       float* s_tmin, float* s_tmax,
                                                       float* smin, float* smax) {
    float lmin = INFINITY, lmax = -INFINITY;
    for (int i = threadIdx.x; i < K1_BLOCKS; i += blockDim.x) {
        lmin = fminf(lmin, ws[16 + i]);
        lmax = fmaxf(lmax, ws[16 + K1_BLOCKS + i]);
    }
    #pragma unroll
    for (int off = 32; off > 0; off >>= 1) {
        lmin = fminf(lmin, __shfl_down(lmin, off, 64));
        lmax = fmaxf(lmax, __shfl_down(lmax, off, 64));
    }
    int lane = threadIdx.x & 63, wid = threadIdx.x >> 6;
    if (lane == 0) { smin[wid] = lmin; smax[wid] = lmax; }
    __syncthreads();
    if (threadIdx.x == 0) {
        float a = smin[0], b = smax[0];
        int nw = blockDim.x >> 6;
        for (int w = 1; w < nw; ++w) { a = fminf(a, smin[w]); b = fmaxf(b, smax[w]); }
        *s_tmin = a;
        *s_tmax = b;
    }
    __syncthreads();
}

__global__ void __launch_bounds__(THREADS) cvar_pass2(const float* __restrict__ pnl,
                                                      int n, float* __restrict__ ws,
                                                      int nb) {
    __shared__ unsigned long long h[NSUB][HPAD];
    __shared__ float smin[NWAVES], smax[NWAVES];
    __shared__ float s_tmin, s_tmax;

    for (int i = threadIdx.x; i < NSUB * HPAD; i += THREADS) (&h[0][0])[i] = 0ull;
    reduce_minmax_partials(ws, &s_tmin, &s_tmax, smin, smax);

    const float t_min = s_tmin, t_max = s_tmax;
    const float range = t_max - t_min;
    const float inv_dt = (range > 0.0f) ? (float)(T_SAMPLES - 1) / range : 0.0f;

    const int sub = (threadIdx.x >> 5) & (NSUB - 1);
    int tid = blockIdx.x * THREADS + threadIdx.x;
    int stride = gridDim.x * THREADS;
    int n4 = n >> 2;
    const float4* p4 = (const float4*)pnl;
    for (int i = tid; i < n4; i += stride) {
        float4 v = p4[i];
        float l[4] = {-v.x, -v.y, -v.z, -v.w};
        #pragma unroll
        for (int k = 0; k < 4; ++k) {
            float x = (l[k] - t_min) * inv_dt;
            int b = (int)x;
            b = b < 0 ? 0 : (b > T_SAMPLES - 1 ? T_SAMPLES - 1 : b);
            float frac = x - (float)b;
            unsigned of = (unsigned)(fminf(frac, 0.99999994f) * 2147483648.0f);
            atomicAdd(&h[sub][b], (1ull << 45) | (unsigned long long)of);
        }
    }
    for (int i = (n4 << 2) + tid; i < n; i += stride) {
        float l = -pnl[i];
        float x = (l - t_min) * inv_dt;
        int b = (int)x;
        b = b < 0 ? 0 : (b > T_SAMPLES - 1 ? T_SAMPLES - 1 : b);
        float frac = x - (float)b;
        unsigned of = (unsigned)(fminf(frac, 0.99999994f) * 2147483648.0f);
        atomicAdd(&h[sub][b], (1ull << 45) | (unsigned long long)of);
    }
    __syncthreads();

    // merge sub-hists -> transposed private slot (plain stores; no field overflow:
    // count <= 7812 < 2^19, ofs <= 7812*2^31 < 2^45)
    if (threadIdx.x < T_SAMPLES) {
        unsigned long long acc = 0ull;
        #pragma unroll
        for (int s = 0; s < NSUB; ++s) acc += h[s][threadIdx.x];
        ((unsigned long long*)ws)[PART64 + (size_t)threadIdx.x * nb + blockIdx.x] = acc;
    }
}

// 100 blocks: block j reduces its bin's nb packed partials (contiguous, coalesced).
__global__ void __launch_bounds__(THREADS) cvar_binreduce(float* __restrict__ ws, int nb) {
    const unsigned long long* src =
        (const unsigned long long*)ws + PART64 + (size_t)blockIdx.x * nb;
    unsigned long long cnt = 0ull, ofs = 0ull;
    for (int b = threadIdx.x; b < nb; b += THREADS) {
        unsigned long long p = src[b];
        cnt += p >> 45;
        ofs += p & ((1ull << 45) - 1ull);
    }
    #pragma unroll
    for (int off = 32; off > 0; off >>= 1) {
        cnt += __shfl_down(cnt, off, 64);
        ofs += __shfl_down(ofs, off, 64);
    }
    __shared__ unsigned long long sc[NWAVES], so[NWAVES];
    int lane = threadIdx.x & 63, wid = threadIdx.x >> 6;
    if (lane == 0) { sc[wid] = cnt; so[wid] = ofs; }
    __syncthreads();
    if (threadIdx.x == 0) {
        unsigned long long C = sc[0], O = so[0];
        for (int w = 1; w < NWAVES; ++w) { C += sc[w]; O += so[w]; }
        ((double*)ws)[FINAL_C + blockIdx.x] = (double)C;
        ((double*)ws)[FINAL_O + blockIdx.x] = (double)O;
    }
}

__global__ void __launch_bounds__(128) cvar_final(const float* __restrict__ ws,
                                                  float* __restrict__ out, int n) {
    __shared__ float smin[2], smax[2];
    __shared__ float s_tmin, s_tmax;
    __shared__ double dc[T_SAMPLES], dofs[T_SAMPLES];
    __shared__ float sred[2];

    reduce_minmax_partials(ws, &s_tmin, &s_tmax, smin, smax);
    const float t_min = s_tmin, t_max = s_tmax;
    const float range = t_max - t_min;
    const float dt = range / (float)(T_SAMPLES - 1);

    int j = threadIdx.x;
    if (j < T_SAMPLES) {
        dc[j] = ((const double*)ws)[FINAL_C + j];
        dofs[j] = ((const double*)ws)[FINAL_O + j];
    }
    __syncthreads();

    float cvar = INFINITY;
    if (j < T_SAMPLES) {
        double C = 0.0, O = 0.0, W = 0.0;
        for (int k = j; k < T_SAMPLES; ++k) {
            C += dc[k];
            O += dofs[k];
            W += (double)(k - j) * dc[k];
        }
        // S(t_j) = sum_{k>=j} [ ofs_k*dt/2^31 + (k-j)*dt*C_k ]
        double S = O * ((double)dt / 2147483648.0) + (double)dt * W;
        float tj = (j == T_SAMPLES - 1) ? t_max : t_min + (float)j * dt;
        cvar = tj + (float)(S * (20.0 / (double)n));
        (void)C;
    }
    #pragma unroll
    for (int off = 32; off > 0; off >>= 1)
        cvar = fminf(cvar, __shfl_down(cvar, off, 64));
    int lane = threadIdx.x & 63, wid = threadIdx.x >> 6;
    if (lane == 0) sred[wid] = cvar;
    __syncthreads();
    if (threadIdx.x == 0) out[0] = fminf(sred[0], sred[1]);
}

extern "C" void kernel_launch(void* const* d_in, const int* in_sizes, int n_in,
                              void* d_out, int out_size, void* d_ws, size_t ws_size,
                              hipStream_t stream) {
    const float* pnl = (const float*)d_in[0];
    int n = in_sizes[0];
    float* ws = (float*)d_ws;
    float* out = (float*)d_out;

    // adapt histogram block count to workspace (needs (PART64 + 100*nb)*8 + finals)
    long avail_u64 = (long)(ws_size / 8) - PART64 - 512;
    int nb = (int)(avail_u64 / T_SAMPLES);
    nb = nb < 8 ? 8 : (nb > HB_MAX ? HB_MAX : nb);

    cvar_pass1<<<K1_BLOCKS, THREADS, 0, stream>>>(pnl, n, ws);
    cvar_pass2<<<nb, THREADS, 0, stream>>>(pnl, n, ws, nb);
    cvar_binreduce<<<T_SAMPLES, THREADS, 0, stream>>>(ws, nb);
    cvar_final<<<1, 128, 0, stream>>>(ws, out, n);
}